// Round 22
// baseline (271.387 us; speedup 1.0000x reference)
//
#include <hip/hip_runtime.h>
#include <math.h>

#define NN   65536      // total nodes
#define NPG  4096       // nodes per graph
#define NB   16         // graphs
#define NE   524288     // real edges
#define EPG  32768      // edges per graph
#define SB   8          // sub-blocks per graph (4096 edges each)
#define NH   128        // hidden
#define FN   8          // node feat
#define FE   4          // edge feat
#define NG   16         // global feat
#define NA   10         // actions
#define NFRAG 2048      // B fragments per matrix: 8 ct x 4 kg x 64 lanes
#define L1B  512        // lin1 blocks (128 nodes each)

typedef __attribute__((ext_vector_type(8))) short bf16x8;
typedef __attribute__((ext_vector_type(4))) float f32x4;

static __device__ __forceinline__ short bf16rne(float f) {
    unsigned u = __builtin_bit_cast(unsigned, f);
    u += 0x7FFFu + ((u >> 16) & 1u);
    return (short)(u >> 16);
}

// ---------------- K1: CSR fill w/ SELF-histogram (128) + W2 frags (2) + lin1 (512) ----------------
// Each csr block histograms its whole graph's dst list itself (128KB, L2-resident
// across the graph's 8 blocks) -> no separate hist kernel, no subhist round-trip.
// hpre counts chunks < sb for the cursor base. lin1 blocks backfill idle CUs.
__global__ __launch_bounds__(1024) void csr_lin1_kernel(
        const int* __restrict__ ei,
        int* __restrict__ offs, int2* __restrict__ csr,
        const float* __restrict__ x,
        const float* __restrict__ Wl, const float* __restrict__ Wr,
        const float* __restrict__ Wl2, const float* __restrict__ Wr2,
        bf16x8* __restrict__ wbf,
        float* __restrict__ xl, float* __restrict__ xr) {
    int bid = blockIdx.x;
    int t = threadIdx.x;
    if (bid < NB * SB) {
        __shared__ int htot[NPG];     // 16 KB: total degree -> scan source
        __shared__ int hpre[NPG];     // 16 KB: degree in chunks < sb -> cursor base
        __shared__ int psum[1024];    //  4 KB
        int g = bid >> 3, sb = bid & 7;
        for (int i = t; i < NPG; i += 1024) { htot[i] = 0; hpre[i] = 0; }
        __syncthreads();
        const int* dstp = ei + NE + g * EPG;
        for (int s = 0; s < SB; ++s) {
            bool pre = s < sb;
            const int* dc = dstp + s * (EPG / SB);
            for (int i = t; i < EPG / SB; i += 1024) {
                int dl = dc[i] - g * NPG;
                atomicAdd(&htot[dl], 1);
                if (pre) atomicAdd(&hpre[dl], 1);
            }
        }
        __syncthreads();
        int base4 = t * 4;
        int loc[4];
        int run = 0;
#pragma unroll
        for (int i = 0; i < 4; ++i) { loc[i] = run; run += htot[base4 + i]; }
        psum[t] = run;
        __syncthreads();
        for (int s = 1; s < 1024; s <<= 1) {
            int add = (t >= s) ? psum[t - s] : 0;
            __syncthreads();
            psum[t] += add;
            __syncthreads();
        }
        int prefix = (t == 0) ? 0 : psum[t - 1];
        int ebase = g * EPG;
#pragma unroll
        for (int i = 0; i < 4; ++i) {
            int nl = base4 + i;
            int off = ebase + prefix + loc[i];
            hpre[nl] += off;                 // hpre becomes the LDS cursor
            if (sb == 0) offs[g * NPG + nl] = off;
        }
        if (sb == 0 && g == NB - 1 && t == 0) offs[NN] = NE;
        __syncthreads();
        int e0 = g * EPG + sb * (EPG / SB);
#pragma unroll
        for (int i = 0; i < (EPG / SB) / 1024; ++i) {
            int e = e0 + i * 1024 + t;
            int dst = ei[NE + e];
            int src = ei[e];
            int pos = atomicAdd(&hpre[dst - g * NPG], 1);
            csr[pos] = make_int2(src, e);
        }
    } else if (bid < NB * SB + 2) {
        int sel = bid - NB * SB;
        const float* W = sel ? Wr2 : Wl2;
#pragma unroll
        for (int q = 0; q < 2; ++q) {
            int f = t * 2 + q;
            int lane = f & 63;
            int kgct = f >> 6;
            int kg = kgct & 3, ct = kgct >> 2;
            int kbase = kg * 32 + (lane >> 4) * 8;
            int c = ct * 16 + (lane & 15);
            bf16x8 v;
#pragma unroll
            for (int j = 0; j < 8; ++j)
                v[j] = bf16rne(W[(kbase + j) * NH + c]);
            wbf[sel * NFRAG + f] = v;
        }
    } else {
        int lb = bid - NB * SB - 2;        // 0..511
        int k = t & 127;
        int oct = t >> 7;                  // 0..7
        float wl[FN], wr[FN];
#pragma unroll
        for (int j = 0; j < FN; ++j) {
            wl[j] = Wl[j * NH + k];
            wr[j] = Wr[j * NH + k];
        }
        int nbase = lb * 128 + oct * 16;
        for (int i = 0; i < 16; ++i) {
            int n = nbase + i;
            float4 xa = *(const float4*)&x[(size_t)n * FN];
            float4 xb = *(const float4*)&x[(size_t)n * FN + 4];
            float al = xa.x * wl[0] + xa.y * wl[1] + xa.z * wl[2] + xa.w * wl[3]
                     + xb.x * wl[4] + xb.y * wl[5] + xb.z * wl[6] + xb.w * wl[7];
            float ar = xa.x * wr[0] + xa.y * wr[1] + xa.z * wr[2] + xa.w * wr[3]
                     + xb.x * wr[4] + xb.y * wr[5] + xb.z * wr[6] + xb.w * wr[7];
            xl[(size_t)n * NH + k] = al;
            xr[(size_t)n * NH + k] = ar;
        }
    }
}

// ---------------- GATv2 gather: one 32-lane group per node (measured-best config — FROZEN loop) ----------------
// Epilogues: MODE-1 writes h as bf16 A-fragments. MODE-2 writes ONLY the 2 pipe-node
// rows per graph + non-atomic gpart pool partials (gsum atomics serialized: r18 +51us).
__global__ __launch_bounds__(256) void gat_gather_kernel(
        const float4* __restrict__ xl, const float4* __restrict__ xr,
        const float4* __restrict__ ea,
        const int2* __restrict__ csr, const int* __restrict__ offs,
        const float* __restrict__ We, const float* __restrict__ att,
        const float* __restrict__ bias,
        unsigned short* __restrict__ hbf_out,
        float4* __restrict__ lattr_w, const float4* __restrict__ lattr_r,
        float4* __restrict__ gpart, float4* __restrict__ pipe,
        const int* __restrict__ cpn, int do_relu) {
    __shared__ float4 red[8][32];
    int grp = threadIdx.x >> 5;
    int lane = threadIdx.x & 31;
    int bid = blockIdx.x;
    int xcd = bid & 7, slot = bid >> 3;
    int g = xcd + ((slot >> 9) << 3);   // graphs {xcd, xcd+8}
    int blk = slot & 511;               // block within graph (512 x 8 nodes)
    int node = g * NPG + blk * 8 + grp;

    float4 xr4 = xr[node * 32 + lane];
    float4 att4 = ((const float4*)att)[lane];
    const float4* We4 = (const float4*)We;
    float4 we0 = We4[lane];
    float4 we1 = We4[32 + lane];
    float4 we2 = We4[64 + lane];
    float4 we3 = We4[96 + lane];

    int beg = offs[node], end = offs[node + 1];
    float l = 0.f;
    float4 acc = make_float4(0.f, 0.f, 0.f, 0.f);
    float4 easum = make_float4(0.f, 0.f, 0.f, 0.f);
    bool have_lattr = (lattr_r != nullptr);
    if (beg < end) {
        int last = end - 1;
        int2 se0 = csr[beg];
        int p1 = (beg + 1 <= last) ? beg + 1 : last;
        int2 se1 = csr[p1];
        float4 xl0 = xl[se0.x * 32 + lane];
        float4 a0 = ea[se0.y];
        for (int p = beg; p < end; ++p) {
            int p2 = (p + 2 <= last) ? p + 2 : last;
            int2 se2 = csr[p2];                       // index prefetch, depth 2
            float4 xl1 = xl[se1.x * 32 + lane];       // data prefetch, depth 1
            float4 a1 = ea[se1.y];
            if (!have_lattr) {
                easum.x += a0.x; easum.y += a0.y; easum.z += a0.z; easum.w += a0.w;
            }
            float tx = xl0.x + xr4.x + a0.x * we0.x + a0.y * we1.x + a0.z * we2.x + a0.w * we3.x;
            float ty = xl0.y + xr4.y + a0.x * we0.y + a0.y * we1.y + a0.z * we2.y + a0.w * we3.y;
            float tz = xl0.z + xr4.z + a0.x * we0.z + a0.y * we1.z + a0.z * we2.z + a0.w * we3.z;
            float tw = xl0.w + xr4.w + a0.x * we0.w + a0.y * we1.w + a0.z * we2.w + a0.w * we3.w;
            tx = tx > 0.f ? tx : 0.2f * tx;
            ty = ty > 0.f ? ty : 0.2f * ty;
            tz = tz > 0.f ? tz : 0.2f * tz;
            tw = tw > 0.f ? tw : 0.2f * tw;
            float s = tx * att4.x + ty * att4.y + tz * att4.z + tw * att4.w;
#pragma unroll
            for (int o = 16; o >= 1; o >>= 1) s += __shfl_xor(s, o);   // stays in 32-group
            float w = __expf(s);
            l += w;
            acc.x += w * xl0.x;
            acc.y += w * xl0.y;
            acc.z += w * xl0.z;
            acc.w += w * xl0.w;
            se1 = se2; xl0 = xl1; a0 = a1;
        }
    }
    // self-loop: src = node, attr = mean incoming ea
    {
        float ax, ay, az, aw;
        if (have_lattr) {
            float4 la = lattr_r[node];
            ax = la.x; ay = la.y; az = la.z; aw = la.w;
        } else {
            int deg = end - beg;
            float invd = 1.0f / (float)(deg > 0 ? deg : 1);
            ax = easum.x * invd; ay = easum.y * invd;
            az = easum.z * invd; aw = easum.w * invd;
            if (lane == 0) lattr_w[node] = make_float4(ax, ay, az, aw);
        }
        float4 xl4 = xl[node * 32 + lane];
        float tx = xl4.x + xr4.x + ax * we0.x + ay * we1.x + az * we2.x + aw * we3.x;
        float ty = xl4.y + xr4.y + ax * we0.y + ay * we1.y + az * we2.y + aw * we3.y;
        float tz = xl4.z + xr4.z + ax * we0.z + ay * we1.z + az * we2.z + aw * we3.z;
        float tw = xl4.w + xr4.w + ax * we0.w + ay * we1.w + az * we2.w + aw * we3.w;
        tx = tx > 0.f ? tx : 0.2f * tx;
        ty = ty > 0.f ? ty : 0.2f * ty;
        tz = tz > 0.f ? tz : 0.2f * tz;
        tw = tw > 0.f ? tw : 0.2f * tw;
        float s = tx * att4.x + ty * att4.y + tz * att4.z + tw * att4.w;
#pragma unroll
        for (int o = 16; o >= 1; o >>= 1) s += __shfl_xor(s, o);
        float w = __expf(s);
        l += w;
        acc.x += w * xl4.x;
        acc.y += w * xl4.y;
        acc.z += w * xl4.z;
        acc.w += w * xl4.w;
    }
    float inv = 1.0f / l;
    float4 b4 = ((const float4*)bias)[lane];
    float4 o4;
    o4.x = acc.x * inv + b4.x;
    o4.y = acc.y * inv + b4.y;
    o4.z = acc.z * inv + b4.z;
    o4.w = acc.w * inv + b4.w;
    if (do_relu) {
        o4.x = fmaxf(o4.x, 0.f); o4.y = fmaxf(o4.y, 0.f);
        o4.z = fmaxf(o4.z, 0.f); o4.w = fmaxf(o4.w, 0.f);
    }
    if (hbf_out != nullptr) {
        // h as bf16 A-fragments: element (m=node&15, k=4*lane+i), rt=node>>4
        int rt = node >> 4, m = node & 15;
        int kg = lane >> 3, qd = (lane & 7) >> 1, j0 = (lane & 1) * 4;
        ushort4 v;
        v.x = (unsigned short)bf16rne(o4.x);
        v.y = (unsigned short)bf16rne(o4.y);
        v.z = (unsigned short)bf16rne(o4.z);
        v.w = (unsigned short)bf16rne(o4.w);
        *(ushort4*)&hbf_out[(size_t)(((rt * 4 + kg) * 64 + qd * 16 + m)) * 8 + j0] = v;
    } else {
        // h2 needed only at the 2 pipe nodes per graph
        int nl = node - g * NPG;
        if (nl == cpn[g * 2 + 0]) pipe[(g * 2 + 0) * 32 + lane] = o4;
        if (nl == cpn[g * 2 + 1]) pipe[(g * 2 + 1) * 32 + lane] = o4;
    }

    // fused mean-pool partials: LDS reduce over 8 groups -> one streaming store/block
    if (gpart != nullptr) {
        red[grp][lane] = o4;
        __syncthreads();
        if (grp < 4) {
            float4 o = red[grp + 4][lane];
            red[grp][lane] = make_float4(red[grp][lane].x + o.x, red[grp][lane].y + o.y,
                                         red[grp][lane].z + o.z, red[grp][lane].w + o.w);
        }
        __syncthreads();
        if (grp < 2) {
            float4 o = red[grp + 2][lane];
            red[grp][lane] = make_float4(red[grp][lane].x + o.x, red[grp][lane].y + o.y,
                                         red[grp][lane].z + o.z, red[grp][lane].w + o.w);
        }
        __syncthreads();
        if (grp == 0) {
            float4 a = red[0][lane], b = red[1][lane];
            gpart[(g * 512 + blk) * 32 + lane] =
                make_float4(a.x + b.x, a.y + b.y, a.z + b.z, a.w + b.w);
        }
    }
}

// ---------------- layer-2 projections: bf16 MFMA, A and B fragments straight from global ----------------
__global__ __launch_bounds__(256) void lin2_mfma_kernel(
        const bf16x8* __restrict__ hbf, const bf16x8* __restrict__ wbf,
        float* __restrict__ xl, float* __restrict__ xr) {
    const bf16x8* Bf = wbf + (size_t)blockIdx.y * NFRAG;
    float* C = blockIdx.y ? xr : xl;
    int t = threadIdx.x;
    int wv = t >> 6, lane = t & 63;
    int rt = blockIdx.x * 4 + wv;      // 16-row tile
    int row0 = rt * 16;
    int m = lane & 15, qd = lane >> 4;
    bf16x8 afrag[4];
#pragma unroll
    for (int kg = 0; kg < 4; ++kg)
        afrag[kg] = hbf[(size_t)(rt * 4 + kg) * 64 + lane];
#pragma unroll
    for (int ct = 0; ct < 8; ++ct) {
        f32x4 acc = {0.f, 0.f, 0.f, 0.f};
#pragma unroll
        for (int kg = 0; kg < 4; ++kg) {
            bf16x8 b = Bf[((ct << 2) | kg) * 64 + lane];
            acc = __builtin_amdgcn_mfma_f32_16x16x32_bf16(afrag[kg], b, acc, 0, 0, 0);
        }
        int col = ct * 16 + m;   // C/D layout: col=lane&15, row=(lane>>4)*4+reg (m89)
#pragma unroll
        for (int r = 0; r < 4; ++r)
            C[(size_t)(row0 + qd * 4 + r) * NH + col] = acc[r];
    }
}

// ---------------- head MLP: one 1024-thread block per graph ----------------
__global__ __launch_bounds__(1024) void head_kernel(
        const float* __restrict__ gpart, const float* __restrict__ pipe,
        const float* __restrict__ gstate,
        const float* __restrict__ Wc, const float* __restrict__ bc,
        const float* __restrict__ Wa1, const float* __restrict__ ba1,
        const float* __restrict__ Wa2, const float* __restrict__ ba2,
        const float* __restrict__ Wv1, const float* __restrict__ bv1,
        const float* __restrict__ Wv2, const float* __restrict__ bv2,
        float* __restrict__ out) {
    int b = blockIdx.x, t = threadIdx.x;
    __shared__ float comb[400];
    __shared__ float part[4][256];
    __shared__ float pp[8][128];
    __shared__ float feat[256];
    __shared__ float hid[256];
    {
        int d = t & 127, p = t >> 7;
        const float* gp = gpart + (size_t)b * 512 * NH + d;
        float s = 0.f;
        int c0 = p * 64;
        for (int c = c0; c < c0 + 64; ++c) s += gp[c * NH];
        pp[p][d] = s;
    }
    if (t >= 128 && t < 384) comb[t] = pipe[(size_t)b * 2 * NH + (t - 128)];
    else if (t >= 384 && t < 400) comb[t] = gstate[b * NG + (t - 384)];
    __syncthreads();
    if (t < 128) {
        float s = pp[0][t] + pp[1][t] + pp[2][t] + pp[3][t]
                + pp[4][t] + pp[5][t] + pp[6][t] + pp[7][t];
        comb[t] = s * (1.0f / NPG);
    }
    __syncthreads();
    {
        int col = t & 255, p = t >> 8;
        float a = 0.f;
        int j0 = p * 100;
        for (int j = j0; j < j0 + 100; ++j) a += comb[j] * Wc[j * 256 + col];
        part[p][col] = a;
    }
    __syncthreads();
    if (t < 256)
        feat[t] = fmaxf(bc[t] + part[0][t] + part[1][t] + part[2][t] + part[3][t], 0.f);
    __syncthreads();
    {
        int col = t & 255, p = t >> 8;
        const float* W = (col < 128) ? Wa1 : Wv1;
        int cc = col & 127;
        float a = 0.f;
        int j0 = p * 64;
        for (int j = j0; j < j0 + 64; ++j) a += feat[j] * W[j * 128 + cc];
        part[p][col] = a;
    }
    __syncthreads();
    if (t < 256) {
        float bias = (t < 128) ? ba1[t] : bv1[t - 128];
        hid[t] = fmaxf(bias + part[0][t] + part[1][t] + part[2][t] + part[3][t], 0.f);
    }
    __syncthreads();
    if (t < NA) {
        float a2 = ba2[t];
        for (int j = 0; j < NH; ++j) a2 += hid[j] * Wa2[j * NA + t];
        out[b * 11 + t] = a2;
    } else if (t == NA) {
        float a2 = bv2[0];
        for (int j = 0; j < NH; ++j) a2 += hid[128 + j] * Wv2[j];
        out[b * 11 + 10] = a2;
    }
}

extern "C" void kernel_launch(void* const* d_in, const int* in_sizes, int n_in,
                              void* d_out, int out_size, void* d_ws, size_t ws_size,
                              hipStream_t stream) {
    const float* x      = (const float*)d_in[0];
    const int*   ei     = (const int*)d_in[1];
    const float* ea     = (const float*)d_in[2];
    const float* gstate = (const float*)d_in[3];
    const int*   cpn    = (const int*)d_in[4];
    const float* Wl1 = (const float*)d_in[5];
    const float* Wr1 = (const float*)d_in[6];
    const float* We1 = (const float*)d_in[7];
    const float* att1= (const float*)d_in[8];
    const float* b1  = (const float*)d_in[9];
    const float* Wl2 = (const float*)d_in[10];
    const float* Wr2 = (const float*)d_in[11];
    const float* We2 = (const float*)d_in[12];
    const float* att2= (const float*)d_in[13];
    const float* b2  = (const float*)d_in[14];
    const float* Wc  = (const float*)d_in[15];
    const float* bc  = (const float*)d_in[16];
    const float* Wa1 = (const float*)d_in[17];
    const float* ba1 = (const float*)d_in[18];
    const float* Wa2 = (const float*)d_in[19];
    const float* ba2 = (const float*)d_in[20];
    const float* Wv1 = (const float*)d_in[21];
    const float* bv1 = (const float*)d_in[22];
    const float* Wv2 = (const float*)d_in[23];
    const float* bv2 = (const float*)d_in[24];

    char* ws = (char*)d_ws;
    size_t o = 0;
    float* xl     = (float*)(ws + o); o += (size_t)NN * NH * 4;   // 32 MB
    float* xr     = (float*)(ws + o); o += (size_t)NN * NH * 4;   // 32 MB
    unsigned short* hbf = (unsigned short*)(ws + o); o += (size_t)NN * NH * 2;  // 16 MB
    float* lattr  = (float*)(ws + o); o += (size_t)NN * 16;       // 1 MB
    float* gpart  = (float*)(ws + o); o += (size_t)NB * 512 * NH * 4;  // 4 MB
    float* pipe   = (float*)(ws + o); o += (size_t)NB * 2 * NH * 4;    // 16 KB
    int*   offs   = (int*)(ws + o);   o += (((size_t)(NN + 1) * 4 + 255) & ~(size_t)255);
    int2*  csr    = (int2*)(ws + o);  o += (size_t)NE * 8;        // 4 MB
    bf16x8* wbf   = (bf16x8*)(ws + o); o += (size_t)2 * NFRAG * 16;  // 64 KB
    (void)o; (void)ws_size; (void)in_sizes; (void)n_in; (void)out_size;

    csr_lin1_kernel<<<NB * SB + 2 + L1B, 1024, 0, stream>>>(ei, offs, csr,
        x, Wl1, Wr1, Wl2, Wr2, wbf, xl, xr);
    gat_gather_kernel<<<NN / 8, 256, 0, stream>>>((const float4*)xl, (const float4*)xr,
        (const float4*)ea, csr, offs, We1, att1, b1, hbf,
        (float4*)lattr, nullptr, nullptr, nullptr, cpn, 1);
    lin2_mfma_kernel<<<dim3(NN / 64, 2), 256, 0, stream>>>((const bf16x8*)hbf, wbf, xl, xr);
    gat_gather_kernel<<<NN / 8, 256, 0, stream>>>((const float4*)xl, (const float4*)xr,
        (const float4*)ea, csr, offs, We2, att2, b2, nullptr,
        nullptr, (const float4*)lattr, (float4*)gpart, (float4*)pipe, cpn, 0);
    head_kernel<<<NB, 1024, 0, stream>>>(gpart, pipe, gstate, Wc, bc, Wa1, ba1, Wa2, ba2,
                                         Wv1, bv1, Wv2, bv2, (float*)d_out);
}

// Round 23
// 269.362 us; speedup vs baseline: 1.0075x; 1.0075x over previous
//
#include <hip/hip_runtime.h>
#include <math.h>

#define NN   65536      // total nodes
#define NPG  4096       // nodes per graph
#define NB   16         // graphs
#define NE   524288     // real edges
#define EPG  32768      // edges per graph
#define SB   8          // sub-blocks per graph (4096 edges each)
#define NH   128        // hidden
#define FN   8          // node feat
#define FE   4          // edge feat
#define NG   16         // global feat
#define NA   10         // actions
#define NFRAG 2048      // B fragments per matrix: 8 ct x 4 kg x 64 lanes
#define L1B  512        // lin1 blocks (128 nodes each)
#define NBIN 32         // degree-sort bins (max degree ~25)

typedef __attribute__((ext_vector_type(8))) short bf16x8;
typedef __attribute__((ext_vector_type(4))) float f32x4;

static __device__ __forceinline__ short bf16rne(float f) {
    unsigned u = __builtin_bit_cast(unsigned, f);
    u += 0x7FFFu + ((u >> 16) & 1u);
    return (short)(u >> 16);
}

// ---------------- K1: CSR fill w/ SELF-histogram (128) + degree-sort perm + W2 frags (2) + lin1 (512) ----------------
// sb==0 blocks additionally counting-sort their graph's nodes by degree -> perm,
// so gat waves/blocks get equal-degree nodes (kills the max(d1,d2) wave divergence
// and gat2's block-barrier straggler tail).
__global__ __launch_bounds__(1024) void csr_lin1_kernel(
        const int* __restrict__ ei,
        int* __restrict__ offs, int2* __restrict__ csr, int* __restrict__ perm,
        const float* __restrict__ x,
        const float* __restrict__ Wl, const float* __restrict__ Wr,
        const float* __restrict__ Wl2, const float* __restrict__ Wr2,
        bf16x8* __restrict__ wbf,
        float* __restrict__ xl, float* __restrict__ xr) {
    int bid = blockIdx.x;
    int t = threadIdx.x;
    if (bid < NB * SB) {
        __shared__ int htot[NPG];     // 16 KB: total degree -> scan source
        __shared__ int hpre[NPG];     // 16 KB: degree in chunks < sb -> cursor base
        __shared__ int psum[1024];    //  4 KB
        __shared__ int bins[NBIN];
        int g = bid >> 3, sb = bid & 7;
        for (int i = t; i < NPG; i += 1024) { htot[i] = 0; hpre[i] = 0; }
        if (t < NBIN) bins[t] = 0;
        __syncthreads();
        const int* dstp = ei + NE + g * EPG;
        for (int s = 0; s < SB; ++s) {
            bool pre = s < sb;
            const int* dc = dstp + s * (EPG / SB);
            for (int i = t; i < EPG / SB; i += 1024) {
                int dl = dc[i] - g * NPG;
                atomicAdd(&htot[dl], 1);
                if (pre) atomicAdd(&hpre[dl], 1);
            }
        }
        __syncthreads();
        int base4 = t * 4;
        int loc[4], dg[4];
        int run = 0;
#pragma unroll
        for (int i = 0; i < 4; ++i) {
            dg[i] = htot[base4 + i];
            loc[i] = run;
            run += dg[i];
        }
        if (sb == 0) {
#pragma unroll
            for (int i = 0; i < 4; ++i) {
                int bi = dg[i] < NBIN ? dg[i] : NBIN - 1;
                atomicAdd(&bins[bi], 1);
            }
        }
        psum[t] = run;
        __syncthreads();
        for (int s = 1; s < 1024; s <<= 1) {
            int add = (t >= s) ? psum[t - s] : 0;
            __syncthreads();
            psum[t] += add;
            __syncthreads();
        }
        int prefix = (t == 0) ? 0 : psum[t - 1];
        int ebase = g * EPG;
#pragma unroll
        for (int i = 0; i < 4; ++i) {
            int nl = base4 + i;
            int off = ebase + prefix + loc[i];
            hpre[nl] += off;                 // hpre becomes the LDS cursor
            if (sb == 0) offs[g * NPG + nl] = off;
        }
        if (sb == 0 && g == NB - 1 && t == 0) offs[NN] = NE;
        if (sb == 0 && t == 0) {             // exclusive scan of degree bins
            int acc = 0;
#pragma unroll
            for (int i = 0; i < NBIN; ++i) { int v = bins[i]; bins[i] = acc; acc += v; }
        }
        __syncthreads();
        if (sb == 0) {                       // counting-sort scatter -> perm (local ids)
#pragma unroll
            for (int i = 0; i < 4; ++i) {
                int nl = base4 + i;
                int bi = dg[i] < NBIN ? dg[i] : NBIN - 1;
                int r = atomicAdd(&bins[bi], 1);
                perm[g * NPG + r] = nl;
            }
        }
        int e0 = g * EPG + sb * (EPG / SB);
#pragma unroll
        for (int i = 0; i < (EPG / SB) / 1024; ++i) {
            int e = e0 + i * 1024 + t;
            int dst = ei[NE + e];
            int src = ei[e];
            int pos = atomicAdd(&hpre[dst - g * NPG], 1);
            csr[pos] = make_int2(src, e);
        }
    } else if (bid < NB * SB + 2) {
        int sel = bid - NB * SB;
        const float* W = sel ? Wr2 : Wl2;
#pragma unroll
        for (int q = 0; q < 2; ++q) {
            int f = t * 2 + q;
            int lane = f & 63;
            int kgct = f >> 6;
            int kg = kgct & 3, ct = kgct >> 2;
            int kbase = kg * 32 + (lane >> 4) * 8;
            int c = ct * 16 + (lane & 15);
            bf16x8 v;
#pragma unroll
            for (int j = 0; j < 8; ++j)
                v[j] = bf16rne(W[(kbase + j) * NH + c]);
            wbf[sel * NFRAG + f] = v;
        }
    } else {
        int lb = bid - NB * SB - 2;        // 0..511
        int k = t & 127;
        int oct = t >> 7;                  // 0..7
        float wl[FN], wr[FN];
#pragma unroll
        for (int j = 0; j < FN; ++j) {
            wl[j] = Wl[j * NH + k];
            wr[j] = Wr[j * NH + k];
        }
        int nbase = lb * 128 + oct * 16;
        for (int i = 0; i < 16; ++i) {
            int n = nbase + i;
            float4 xa = *(const float4*)&x[(size_t)n * FN];
            float4 xb = *(const float4*)&x[(size_t)n * FN + 4];
            float al = xa.x * wl[0] + xa.y * wl[1] + xa.z * wl[2] + xa.w * wl[3]
                     + xb.x * wl[4] + xb.y * wl[5] + xb.z * wl[6] + xb.w * wl[7];
            float ar = xa.x * wr[0] + xa.y * wr[1] + xa.z * wr[2] + xa.w * wr[3]
                     + xb.x * wr[4] + xb.y * wr[5] + xb.z * wr[6] + xb.w * wr[7];
            xl[(size_t)n * NH + k] = al;
            xr[(size_t)n * NH + k] = ar;
        }
    }
}

// ---------------- GATv2 gather: one 32-lane group per node (measured-best config — FROZEN loop) ----------------
// Node assignment now via degree-sorted perm: equal-degree nodes share a wave/block.
// Epilogues: MODE-1 writes h as bf16 A-fragments. MODE-2 writes ONLY the 2 pipe-node
// rows per graph + non-atomic gpart pool partials.
__global__ __launch_bounds__(256) void gat_gather_kernel(
        const float4* __restrict__ xl, const float4* __restrict__ xr,
        const float4* __restrict__ ea,
        const int2* __restrict__ csr, const int* __restrict__ offs,
        const int* __restrict__ perm,
        const float* __restrict__ We, const float* __restrict__ att,
        const float* __restrict__ bias,
        unsigned short* __restrict__ hbf_out,
        float4* __restrict__ lattr_w, const float4* __restrict__ lattr_r,
        float4* __restrict__ gpart, float4* __restrict__ pipe,
        const int* __restrict__ cpn, int do_relu) {
    __shared__ float4 red[8][32];
    int grp = threadIdx.x >> 5;
    int lane = threadIdx.x & 31;
    int bid = blockIdx.x;
    int xcd = bid & 7, slot = bid >> 3;
    int g = xcd + ((slot >> 9) << 3);   // graphs {xcd, xcd+8}
    int blk = slot & 511;               // block within graph (512 x 8 nodes)
    int node = g * NPG + perm[g * NPG + blk * 8 + grp];

    float4 xr4 = xr[node * 32 + lane];
    float4 att4 = ((const float4*)att)[lane];
    const float4* We4 = (const float4*)We;
    float4 we0 = We4[lane];
    float4 we1 = We4[32 + lane];
    float4 we2 = We4[64 + lane];
    float4 we3 = We4[96 + lane];

    int beg = offs[node], end = offs[node + 1];
    float l = 0.f;
    float4 acc = make_float4(0.f, 0.f, 0.f, 0.f);
    float4 easum = make_float4(0.f, 0.f, 0.f, 0.f);
    bool have_lattr = (lattr_r != nullptr);
    if (beg < end) {
        int last = end - 1;
        int2 se0 = csr[beg];
        int p1 = (beg + 1 <= last) ? beg + 1 : last;
        int2 se1 = csr[p1];
        float4 xl0 = xl[se0.x * 32 + lane];
        float4 a0 = ea[se0.y];
        for (int p = beg; p < end; ++p) {
            int p2 = (p + 2 <= last) ? p + 2 : last;
            int2 se2 = csr[p2];                       // index prefetch, depth 2
            float4 xl1 = xl[se1.x * 32 + lane];       // data prefetch, depth 1
            float4 a1 = ea[se1.y];
            if (!have_lattr) {
                easum.x += a0.x; easum.y += a0.y; easum.z += a0.z; easum.w += a0.w;
            }
            float tx = xl0.x + xr4.x + a0.x * we0.x + a0.y * we1.x + a0.z * we2.x + a0.w * we3.x;
            float ty = xl0.y + xr4.y + a0.x * we0.y + a0.y * we1.y + a0.z * we2.y + a0.w * we3.y;
            float tz = xl0.z + xr4.z + a0.x * we0.z + a0.y * we1.z + a0.z * we2.z + a0.w * we3.z;
            float tw = xl0.w + xr4.w + a0.x * we0.w + a0.y * we1.w + a0.z * we2.w + a0.w * we3.w;
            tx = tx > 0.f ? tx : 0.2f * tx;
            ty = ty > 0.f ? ty : 0.2f * ty;
            tz = tz > 0.f ? tz : 0.2f * tz;
            tw = tw > 0.f ? tw : 0.2f * tw;
            float s = tx * att4.x + ty * att4.y + tz * att4.z + tw * att4.w;
#pragma unroll
            for (int o = 16; o >= 1; o >>= 1) s += __shfl_xor(s, o);   // stays in 32-group
            float w = __expf(s);
            l += w;
            acc.x += w * xl0.x;
            acc.y += w * xl0.y;
            acc.z += w * xl0.z;
            acc.w += w * xl0.w;
            se1 = se2; xl0 = xl1; a0 = a1;
        }
    }
    // self-loop: src = node, attr = mean incoming ea
    {
        float ax, ay, az, aw;
        if (have_lattr) {
            float4 la = lattr_r[node];
            ax = la.x; ay = la.y; az = la.z; aw = la.w;
        } else {
            int deg = end - beg;
            float invd = 1.0f / (float)(deg > 0 ? deg : 1);
            ax = easum.x * invd; ay = easum.y * invd;
            az = easum.z * invd; aw = easum.w * invd;
            if (lane == 0) lattr_w[node] = make_float4(ax, ay, az, aw);
        }
        float4 xl4 = xl[node * 32 + lane];
        float tx = xl4.x + xr4.x + ax * we0.x + ay * we1.x + az * we2.x + aw * we3.x;
        float ty = xl4.y + xr4.y + ax * we0.y + ay * we1.y + az * we2.y + aw * we3.y;
        float tz = xl4.z + xr4.z + ax * we0.z + ay * we1.z + az * we2.z + aw * we3.z;
        float tw = xl4.w + xr4.w + ax * we0.w + ay * we1.w + az * we2.w + aw * we3.w;
        tx = tx > 0.f ? tx : 0.2f * tx;
        ty = ty > 0.f ? ty : 0.2f * ty;
        tz = tz > 0.f ? tz : 0.2f * tz;
        tw = tw > 0.f ? tw : 0.2f * tw;
        float s = tx * att4.x + ty * att4.y + tz * att4.z + tw * att4.w;
#pragma unroll
        for (int o = 16; o >= 1; o >>= 1) s += __shfl_xor(s, o);
        float w = __expf(s);
        l += w;
        acc.x += w * xl4.x;
        acc.y += w * xl4.y;
        acc.z += w * xl4.z;
        acc.w += w * xl4.w;
    }
    float inv = 1.0f / l;
    float4 b4 = ((const float4*)bias)[lane];
    float4 o4;
    o4.x = acc.x * inv + b4.x;
    o4.y = acc.y * inv + b4.y;
    o4.z = acc.z * inv + b4.z;
    o4.w = acc.w * inv + b4.w;
    if (do_relu) {
        o4.x = fmaxf(o4.x, 0.f); o4.y = fmaxf(o4.y, 0.f);
        o4.z = fmaxf(o4.z, 0.f); o4.w = fmaxf(o4.w, 0.f);
    }
    if (hbf_out != nullptr) {
        // h as bf16 A-fragments: element (m=node&15, k=4*lane+i), rt=node>>4
        int rt = node >> 4, m = node & 15;
        int kg = lane >> 3, qd = (lane & 7) >> 1, j0 = (lane & 1) * 4;
        ushort4 v;
        v.x = (unsigned short)bf16rne(o4.x);
        v.y = (unsigned short)bf16rne(o4.y);
        v.z = (unsigned short)bf16rne(o4.z);
        v.w = (unsigned short)bf16rne(o4.w);
        *(ushort4*)&hbf_out[(size_t)(((rt * 4 + kg) * 64 + qd * 16 + m)) * 8 + j0] = v;
    } else {
        // h2 needed only at the 2 pipe nodes per graph
        int nl = node - g * NPG;
        if (nl == cpn[g * 2 + 0]) pipe[(g * 2 + 0) * 32 + lane] = o4;
        if (nl == cpn[g * 2 + 1]) pipe[(g * 2 + 1) * 32 + lane] = o4;
    }

    // fused mean-pool partials: LDS reduce over 8 groups -> one streaming store/block
    if (gpart != nullptr) {
        red[grp][lane] = o4;
        __syncthreads();
        if (grp < 4) {
            float4 o = red[grp + 4][lane];
            red[grp][lane] = make_float4(red[grp][lane].x + o.x, red[grp][lane].y + o.y,
                                         red[grp][lane].z + o.z, red[grp][lane].w + o.w);
        }
        __syncthreads();
        if (grp < 2) {
            float4 o = red[grp + 2][lane];
            red[grp][lane] = make_float4(red[grp][lane].x + o.x, red[grp][lane].y + o.y,
                                         red[grp][lane].z + o.z, red[grp][lane].w + o.w);
        }
        __syncthreads();
        if (grp == 0) {
            float4 a = red[0][lane], b = red[1][lane];
            gpart[(g * 512 + blk) * 32 + lane] =
                make_float4(a.x + b.x, a.y + b.y, a.z + b.z, a.w + b.w);
        }
    }
}

// ---------------- layer-2 projections: bf16 MFMA, A and B fragments straight from global ----------------
__global__ __launch_bounds__(256) void lin2_mfma_kernel(
        const bf16x8* __restrict__ hbf, const bf16x8* __restrict__ wbf,
        float* __restrict__ xl, float* __restrict__ xr) {
    const bf16x8* Bf = wbf + (size_t)blockIdx.y * NFRAG;
    float* C = blockIdx.y ? xr : xl;
    int t = threadIdx.x;
    int wv = t >> 6, lane = t & 63;
    int rt = blockIdx.x * 4 + wv;      // 16-row tile
    int row0 = rt * 16;
    int m = lane & 15, qd = lane >> 4;
    bf16x8 afrag[4];
#pragma unroll
    for (int kg = 0; kg < 4; ++kg)
        afrag[kg] = hbf[(size_t)(rt * 4 + kg) * 64 + lane];
#pragma unroll
    for (int ct = 0; ct < 8; ++ct) {
        f32x4 acc = {0.f, 0.f, 0.f, 0.f};
#pragma unroll
        for (int kg = 0; kg < 4; ++kg) {
            bf16x8 b = Bf[((ct << 2) | kg) * 64 + lane];
            acc = __builtin_amdgcn_mfma_f32_16x16x32_bf16(afrag[kg], b, acc, 0, 0, 0);
        }
        int col = ct * 16 + m;   // C/D layout: col=lane&15, row=(lane>>4)*4+reg (m89)
#pragma unroll
        for (int r = 0; r < 4; ++r)
            C[(size_t)(row0 + qd * 4 + r) * NH + col] = acc[r];
    }
}

// ---------------- head MLP: one 1024-thread block per graph ----------------
__global__ __launch_bounds__(1024) void head_kernel(
        const float* __restrict__ gpart, const float* __restrict__ pipe,
        const float* __restrict__ gstate,
        const float* __restrict__ Wc, const float* __restrict__ bc,
        const float* __restrict__ Wa1, const float* __restrict__ ba1,
        const float* __restrict__ Wa2, const float* __restrict__ ba2,
        const float* __restrict__ Wv1, const float* __restrict__ bv1,
        const float* __restrict__ Wv2, const float* __restrict__ bv2,
        float* __restrict__ out) {
    int b = blockIdx.x, t = threadIdx.x;
    __shared__ float comb[400];
    __shared__ float part[4][256];
    __shared__ float pp[8][128];
    __shared__ float feat[256];
    __shared__ float hid[256];
    {
        int d = t & 127, p = t >> 7;
        const float* gp = gpart + (size_t)b * 512 * NH + d;
        float s = 0.f;
        int c0 = p * 64;
        for (int c = c0; c < c0 + 64; ++c) s += gp[c * NH];
        pp[p][d] = s;
    }
    if (t >= 128 && t < 384) comb[t] = pipe[(size_t)b * 2 * NH + (t - 128)];
    else if (t >= 384 && t < 400) comb[t] = gstate[b * NG + (t - 384)];
    __syncthreads();
    if (t < 128) {
        float s = pp[0][t] + pp[1][t] + pp[2][t] + pp[3][t]
                + pp[4][t] + pp[5][t] + pp[6][t] + pp[7][t];
        comb[t] = s * (1.0f / NPG);
    }
    __syncthreads();
    {
        int col = t & 255, p = t >> 8;
        float a = 0.f;
        int j0 = p * 100;
        for (int j = j0; j < j0 + 100; ++j) a += comb[j] * Wc[j * 256 + col];
        part[p][col] = a;
    }
    __syncthreads();
    if (t < 256)
        feat[t] = fmaxf(bc[t] + part[0][t] + part[1][t] + part[2][t] + part[3][t], 0.f);
    __syncthreads();
    {
        int col = t & 255, p = t >> 8;
        const float* W = (col < 128) ? Wa1 : Wv1;
        int cc = col & 127;
        float a = 0.f;
        int j0 = p * 64;
        for (int j = j0; j < j0 + 64; ++j) a += feat[j] * W[j * 128 + cc];
        part[p][col] = a;
    }
    __syncthreads();
    if (t < 256) {
        float bias = (t < 128) ? ba1[t] : bv1[t - 128];
        hid[t] = fmaxf(bias + part[0][t] + part[1][t] + part[2][t] + part[3][t], 0.f);
    }
    __syncthreads();
    if (t < NA) {
        float a2 = ba2[t];
        for (int j = 0; j < NH; ++j) a2 += hid[j] * Wa2[j * NA + t];
        out[b * 11 + t] = a2;
    } else if (t == NA) {
        float a2 = bv2[0];
        for (int j = 0; j < NH; ++j) a2 += hid[128 + j] * Wv2[j];
        out[b * 11 + 10] = a2;
    }
}

extern "C" void kernel_launch(void* const* d_in, const int* in_sizes, int n_in,
                              void* d_out, int out_size, void* d_ws, size_t ws_size,
                              hipStream_t stream) {
    const float* x      = (const float*)d_in[0];
    const int*   ei     = (const int*)d_in[1];
    const float* ea     = (const float*)d_in[2];
    const float* gstate = (const float*)d_in[3];
    const int*   cpn    = (const int*)d_in[4];
    const float* Wl1 = (const float*)d_in[5];
    const float* Wr1 = (const float*)d_in[6];
    const float* We1 = (const float*)d_in[7];
    const float* att1= (const float*)d_in[8];
    const float* b1  = (const float*)d_in[9];
    const float* Wl2 = (const float*)d_in[10];
    const float* Wr2 = (const float*)d_in[11];
    const float* We2 = (const float*)d_in[12];
    const float* att2= (const float*)d_in[13];
    const float* b2  = (const float*)d_in[14];
    const float* Wc  = (const float*)d_in[15];
    const float* bc  = (const float*)d_in[16];
    const float* Wa1 = (const float*)d_in[17];
    const float* ba1 = (const float*)d_in[18];
    const float* Wa2 = (const float*)d_in[19];
    const float* ba2 = (const float*)d_in[20];
    const float* Wv1 = (const float*)d_in[21];
    const float* bv1 = (const float*)d_in[22];
    const float* Wv2 = (const float*)d_in[23];
    const float* bv2 = (const float*)d_in[24];

    char* ws = (char*)d_ws;
    size_t o = 0;
    float* xl     = (float*)(ws + o); o += (size_t)NN * NH * 4;   // 32 MB
    float* xr     = (float*)(ws + o); o += (size_t)NN * NH * 4;   // 32 MB
    unsigned short* hbf = (unsigned short*)(ws + o); o += (size_t)NN * NH * 2;  // 16 MB
    float* lattr  = (float*)(ws + o); o += (size_t)NN * 16;       // 1 MB
    float* gpart  = (float*)(ws + o); o += (size_t)NB * 512 * NH * 4;  // 4 MB
    float* pipe   = (float*)(ws + o); o += (size_t)NB * 2 * NH * 4;    // 16 KB
    int*   offs   = (int*)(ws + o);   o += (((size_t)(NN + 1) * 4 + 255) & ~(size_t)255);
    int*   perm   = (int*)(ws + o);   o += (size_t)NN * 4;        // 256 KB
    int2*  csr    = (int2*)(ws + o);  o += (size_t)NE * 8;        // 4 MB
    bf16x8* wbf   = (bf16x8*)(ws + o); o += (size_t)2 * NFRAG * 16;  // 64 KB
    (void)o; (void)ws_size; (void)in_sizes; (void)n_in; (void)out_size;

    csr_lin1_kernel<<<NB * SB + 2 + L1B, 1024, 0, stream>>>(ei, offs, csr, perm,
        x, Wl1, Wr1, Wl2, Wr2, wbf, xl, xr);
    gat_gather_kernel<<<NN / 8, 256, 0, stream>>>((const float4*)xl, (const float4*)xr,
        (const float4*)ea, csr, offs, perm, We1, att1, b1, hbf,
        (float4*)lattr, nullptr, nullptr, nullptr, cpn, 1);
    lin2_mfma_kernel<<<dim3(NN / 64, 2), 256, 0, stream>>>((const bf16x8*)hbf, wbf, xl, xr);
    gat_gather_kernel<<<NN / 8, 256, 0, stream>>>((const float4*)xl, (const float4*)xr,
        (const float4*)ea, csr, offs, perm, We2, att2, b2, nullptr,
        nullptr, (const float4*)lattr, (float4*)gpart, (float4*)pipe, cpn, 0);
    head_kernel<<<NB, 1024, 0, stream>>>(gpart, pipe, gstate, Wc, bc, Wa1, ba1, Wa2, ba2,
                                         Wv1, bv1, Wv2, bv2, (float*)d_out);
}